// Round 8
// baseline (128.152 us; speedup 1.0000x reference)
//
#include <hip/hip_runtime.h>
#include <hip/hip_bf16.h>

typedef __attribute__((ext_vector_type(8))) short bf16x8;
typedef __attribute__((ext_vector_type(4))) float f32x4;

__device__ __forceinline__ ushort f2bf(float f) {          // fp32 -> bf16 (RNE)
    unsigned u = __float_as_uint(f);
    return (ushort)((u + 0x7fffu + ((u >> 16) & 1u)) >> 16);
}
__device__ __forceinline__ float blo(unsigned u) { return __uint_as_float(u << 16); }
__device__ __forceinline__ float bhi(unsigned u) { return __uint_as_float(u & 0xffff0000u); }

// ---- K0: W -> bf16 W^T (for MFMA B-frags) + zero deg --------------------------
__global__ void k_wt(const float* __restrict__ W, ushort* __restrict__ Wt,
                     int* __restrict__ deg, int n) {
    int idx = blockIdx.x * 256 + threadIdx.x;
    if (idx < 16384) {
        int nn = idx >> 7, kk = idx & 127;
        Wt[idx] = f2bf(W[kk * 128 + nn]);      // Wt[nn][kk] = W[kk][nn]
    }
    if (idx < n) deg[idx] = 0;
}

// ---- K1: proj = A @ W via bf16 MFMA; fused scores ------------------------------
// block = 256 thr (4 waves), 64 rows/block. LDS: A-tile 16KB + Wt 32KB, both
// XOR-swizzled (byte ^= (row&7)<<4) to kill the 256B-stride bank conflict.
__global__ __launch_bounds__(256) void k_proj(const float* __restrict__ A,
                                              const ushort* __restrict__ Wt_g,
                                              const float* __restrict__ a_src,
                                              const float* __restrict__ a_tgt,
                                              ushort* __restrict__ Pb,
                                              float* __restrict__ ss,
                                              float* __restrict__ ts, int n) {
    __shared__ __align__(16) char smem[49152];  // [0,16K): A 64x128 bf16; [16K,48K): Wt 128x128 bf16
    const int tid = threadIdx.x;
    const int row0 = blockIdx.x * 64;

    // stage A rows (fp32 -> bf16), swizzled
#pragma unroll
    for (int it = 0; it < 8; ++it) {
        int idx = it * 256 + tid;        // 0..2047
        int r   = idx >> 5;              // 0..63
        int kc  = (idx & 31) << 2;       // 0..124
        int gr  = row0 + r;
        float4 v = make_float4(0.f, 0.f, 0.f, 0.f);
        if (gr < n) v = *(const float4*)&A[(size_t)gr * 128 + kc];
        ushort4 pk;
        pk.x = f2bf(v.x); pk.y = f2bf(v.y); pk.z = f2bf(v.z); pk.w = f2bf(v.w);
        *(ushort4*)(smem + ((r * 256 + kc * 2) ^ ((r & 7) << 4))) = pk;
    }
    // stage Wt (bf16, already transposed), swizzled
#pragma unroll
    for (int it = 0; it < 8; ++it) {
        int idx = it * 256 + tid;        // 0..2047
        int nn  = idx >> 4;              // 0..127
        int k8  = (idx & 15) << 3;       // 0..120
        uint4 v = *(const uint4*)&Wt_g[nn * 128 + k8];
        *(uint4*)(smem + 16384 + ((nn * 256 + k8 * 2) ^ ((nn & 7) << 4))) = v;
    }
    __syncthreads();

    const int l  = tid & 63, w = tid >> 6;
    const int lr = l & 15,  lk = l >> 4;
    const int arow = w * 16 + lr;

    f32x4 acc[8] = {};
#pragma unroll
    for (int ks = 0; ks < 4; ++ks) {
        int kk = ks * 32 + lk * 8;
        bf16x8 af = *(const bf16x8*)(smem + ((arow * 256 + kk * 2) ^ ((arow & 7) << 4)));
#pragma unroll
        for (int nt = 0; nt < 8; ++nt) {
            int nn = nt * 16 + lr;
            bf16x8 bf = *(const bf16x8*)(smem + 16384 + ((nn * 256 + kk * 2) ^ ((nn & 7) << 4)));
            acc[nt] = __builtin_amdgcn_mfma_f32_16x16x32_bf16(af, bf, acc[nt], 0, 0, 0);
        }
    }

    // Pb write: D layout col = lane&15 (per tile), row = (lane>>4)*4 + reg
#pragma unroll
    for (int nt = 0; nt < 8; ++nt) {
#pragma unroll
        for (int r = 0; r < 4; ++r) {
            int gr = row0 + w * 16 + lk * 4 + r;
            if (gr < n) Pb[(size_t)gr * 128 + nt * 16 + lr] = f2bf(acc[nt][r]);
        }
    }

    // fused scores from fp32 accumulators (tile t, lane lr -> flat col t*16+lr)
    float av[8], bw[8];
#pragma unroll
    for (int t = 0; t < 8; ++t) { av[t] = a_src[t * 16 + lr]; bw[t] = a_tgt[t * 16 + lr]; }
#pragma unroll
    for (int r = 0; r < 4; ++r) {
#pragma unroll
        for (int h = 0; h < 4; ++h) {
            float s1 = acc[2 * h][r] * av[2 * h] + acc[2 * h + 1][r] * av[2 * h + 1];
            float s2 = acc[2 * h][r] * bw[2 * h] + acc[2 * h + 1][r] * bw[2 * h + 1];
#pragma unroll
            for (int off = 1; off < 16; off <<= 1) {
                s1 += __shfl_xor(s1, off, 64);
                s2 += __shfl_xor(s2, off, 64);
            }
            if (lr == 0) {
                int gr = row0 + w * 16 + lk * 4 + r;
                if (gr < n) { ss[gr * 4 + h] = s1; ts[gr * 4 + h] = s2; }
            }
        }
    }
}

// ---------------- CSR build ----------------------------------------------------
// rank fits ushort: max in-degree of 800K uniform edges over 50K nodes is ~45.
__global__ void k_hist(const int* __restrict__ tgt, int* __restrict__ deg,
                       ushort* __restrict__ rank, int E) {
    int e = blockIdx.x * 256 + threadIdx.x;
    if (e < E) rank[e] = (ushort)atomicAdd(&deg[tgt[e]], 1);
}

// scan of PADDED degrees ((deg+3)&~3) -> CSR rows are multiples of 4 (no tail in aggr)
__global__ __launch_bounds__(256) void k_scan1(const int* __restrict__ deg,
                                               int* __restrict__ rowptr,
                                               int* __restrict__ sums, int n) {
    __shared__ int sd[256];
    int tid = threadIdx.x;
    int i = blockIdx.x * 256 + tid;
    int v = (i < n) ? ((deg[i] + 3) & ~3) : 0;
    sd[tid] = v; __syncthreads();
#pragma unroll
    for (int off = 1; off < 256; off <<= 1) {
        int t = (tid >= off) ? sd[tid - off] : 0;
        __syncthreads();
        sd[tid] += t;
        __syncthreads();
    }
    if (i < n) rowptr[i + 1] = sd[tid];
    if (tid == 255) sums[blockIdx.x] = sd[255];
}

__global__ __launch_bounds__(256) void k_scan23(int* __restrict__ rowptr,
                                                const int* __restrict__ sums,
                                                int nchunks, int n) {
    __shared__ int sd[256];
    int tid = threadIdx.x;
    int v = (tid < nchunks) ? sums[tid] : 0;
    sd[tid] = v; __syncthreads();
#pragma unroll
    for (int off = 1; off < 256; off <<= 1) {
        int t = (tid >= off) ? sd[tid - off] : 0;
        __syncthreads();
        sd[tid] += t;
        __syncthreads();
    }
    int b = blockIdx.x;
    int prefix = (b == 0) ? 0 : sd[b - 1];
    int i = b * 256 + tid;
    if (i < n) {
        rowptr[i + 1] += prefix;
        if (i == 0) rowptr[0] = 0;
    }
}

// ---- scatter (atomic-free) + pad-fill: threads e<E scatter, threads E..E+n pad -
__global__ void k_scatter(const int* __restrict__ src, const int* __restrict__ tgt,
                          const int* __restrict__ rowptr, const ushort* __restrict__ rank,
                          const int* __restrict__ deg, ushort* __restrict__ srcs,
                          int E, int n) {
    int e = blockIdx.x * 256 + threadIdx.x;
    if (e < E) {
        int t = tgt[e];
        srcs[rowptr[t] + rank[e]] = (ushort)src[e];
    } else {
        int i = e - E;
        if (i < n) {
            int j  = rowptr[i] + deg[i];
            int j1 = rowptr[i + 1];
            for (; j < j1; ++j) srcs[j] = 0xFFFFu;   // pad sentinel
        }
    }
}

// ---- aggregation: 1 wave/node, scalarized CSR walk, padded (tail-free) --------
// readfirstlane(node) makes the whole index chain SGPR: rowptr, srcs groups
// (s_load_dwordx2), ss rows (uniform float4) scalar; only Pb gather + head
// select + exp run on the VALU. Pads (0xFFFF) -> score -1e30 -> exp 0.
__global__ __launch_bounds__(256) void k_aggr(const int* __restrict__ rowptr,
                                              const ushort* __restrict__ srcs,
                                              const float* __restrict__ ss,
                                              const float* __restrict__ ts,
                                              const ushort* __restrict__ Pb,
                                              const float* __restrict__ bias,
                                              float* __restrict__ out, int n) {
    int node = __builtin_amdgcn_readfirstlane(blockIdx.x * 4 + (threadIdx.x >> 6));
    if (node >= n) return;
    const int lane = threadIdx.x & 63;
    const int c = lane * 2;
    const int h = lane >> 4;
    const float tsc = ts[node * 4 + h];
    const int b0 = rowptr[node], b1 = rowptr[node + 1];

    float ax0 = 0.f, ay0 = 0.f, ax1 = 0.f, ay1 = 0.f;
    float ax2 = 0.f, ay2 = 0.f, ax3 = 0.f, ay3 = 0.f;
    float den = 0.f;
    for (int i = b0; i < b1; i += 4) {
        uint2 pk = *(const uint2*)(srcs + i);          // uniform -> s_load_dwordx2
        int s0 = pk.x & 0xFFFF, s1 = pk.x >> 16;
        int s2 = pk.y & 0xFFFF, s3 = pk.y >> 16;
        bool v0 = s0 < n, v1 = s1 < n, v2 = s2 < n, v3 = s3 < n;   // pad mask (uniform)
        int m0 = v0 ? s0 : 0, m1 = v1 ? s1 : 0, m2 = v2 ? s2 : 0, m3 = v3 ? s3 : 0;
        float4 r0 = *(const float4*)(ss + m0 * 4);     // uniform row loads
        float4 r1 = *(const float4*)(ss + m1 * 4);
        float4 r2 = *(const float4*)(ss + m2 * 4);
        float4 r3 = *(const float4*)(ss + m3 * 4);
        unsigned p0 = *(const unsigned*)(Pb + (size_t)m0 * 128 + c);
        unsigned p1 = *(const unsigned*)(Pb + (size_t)m1 * 128 + c);
        unsigned p2 = *(const unsigned*)(Pb + (size_t)m2 * 128 + c);
        unsigned p3 = *(const unsigned*)(Pb + (size_t)m3 * 128 + c);
        float sv0 = (h & 2) ? ((h & 1) ? r0.w : r0.z) : ((h & 1) ? r0.y : r0.x);
        float sv1 = (h & 2) ? ((h & 1) ? r1.w : r1.z) : ((h & 1) ? r1.y : r1.x);
        float sv2 = (h & 2) ? ((h & 1) ? r2.w : r2.z) : ((h & 1) ? r2.y : r2.x);
        float sv3 = (h & 2) ? ((h & 1) ? r3.w : r3.z) : ((h & 1) ? r3.y : r3.x);
        sv0 = v0 ? sv0 : -1e30f;   // pad -> exp(-inf) = 0, NaN-free
        sv1 = v1 ? sv1 : -1e30f;
        sv2 = v2 ? sv2 : -1e30f;
        sv3 = v3 ? sv3 : -1e30f;
        float w0 = sv0 + tsc; w0 = w0 > 0.f ? w0 : 0.2f * w0;  float e0 = __expf(w0);
        float w1 = sv1 + tsc; w1 = w1 > 0.f ? w1 : 0.2f * w1;  float e1 = __expf(w1);
        float w2 = sv2 + tsc; w2 = w2 > 0.f ? w2 : 0.2f * w2;  float e2 = __expf(w2);
        float w3 = sv3 + tsc; w3 = w3 > 0.f ? w3 : 0.2f * w3;  float e3 = __expf(w3);
        den += (e0 + e1) + (e2 + e3);
        ax0 = fmaf(e0, blo(p0), ax0); ay0 = fmaf(e0, bhi(p0), ay0);
        ax1 = fmaf(e1, blo(p1), ax1); ay1 = fmaf(e1, bhi(p1), ay1);
        ax2 = fmaf(e2, blo(p2), ax2); ay2 = fmaf(e2, bhi(p2), ay2);
        ax3 = fmaf(e3, blo(p3), ax3); ay3 = fmaf(e3, bhi(p3), ay3);
    }
    float inv = 1.f / (den + 1e-16f);
    float2 bv = *(const float2*)&bias[c];
    float2 o;
    o.x = ((ax0 + ax1) + (ax2 + ax3)) * inv + bv.x;
    o.y = ((ay0 + ay1) + (ay2 + ay3)) * inv + bv.y;
    *(float2*)&out[(size_t)node * 128 + c] = o;
}

extern "C" void kernel_launch(void* const* d_in, const int* in_sizes, int n_in,
                              void* d_out, int out_size, void* d_ws, size_t ws_size,
                              hipStream_t stream) {
    const float* in_feat = (const float*)d_in[0];
    const int*   edge    = (const int*)d_in[1];
    const float* W_proj  = (const float*)d_in[3];
    const float* a_src   = (const float*)d_in[4];
    const float* a_tgt   = (const float*)d_in[5];
    const float* bias    = (const float*)d_in[6];
    float* out = (float*)d_out;

    const int n = in_sizes[0] / 128;   // 50000 (< 65536: ushort srcs/rank valid)
    const int E = in_sizes[1] / 2;     // 800000
    const int* src = edge;
    const int* tgt = edge + E;

    // workspace layout
    ushort* Pb   = (ushort*)d_ws;                      // n*128 bf16
    ushort* Wt_g = Pb + (size_t)n * 128;               // 128*128 bf16
    float*  ss   = (float*)(Wt_g + 128 * 128);         // n*4
    float*  ts   = ss + (size_t)n * 4;                 // n*4
    int* deg    = (int*)(ts + (size_t)n * 4);          // n
    int* rowptr = deg + n;                             // n+1
    int* sums   = rowptr + n + 1;                      // 256
    ushort* rank = (ushort*)(sums + 256);              // E
    ushort* srcs = rank + E;                           // E + 4n (padded CSR)

    const int nchunks = (n + 255) / 256;

    k_wt<<<(n + 255) / 256, 256, 0, stream>>>(W_proj, Wt_g, deg, n);
    k_hist<<<(E + 255) / 256, 256, 0, stream>>>(tgt, deg, rank, E);
    k_proj<<<(n + 63) / 64, 256, 0, stream>>>(in_feat, Wt_g, a_src, a_tgt,
                                              Pb, ss, ts, n);
    k_scan1<<<nchunks, 256, 0, stream>>>(deg, rowptr, sums, n);
    k_scan23<<<nchunks, 256, 0, stream>>>(rowptr, sums, nchunks, n);
    k_scatter<<<(E + n + 255) / 256, 256, 0, stream>>>(src, tgt, rowptr, rank,
                                                       deg, srcs, E, n);
    k_aggr<<<(n + 3) / 4, 256, 0, stream>>>(rowptr, srcs, ss, ts, Pb, bias, out, n);
}

// Round 9
// 115.056 us; speedup vs baseline: 1.1138x; 1.1138x over previous
//
#include <hip/hip_runtime.h>
#include <hip/hip_bf16.h>

typedef __attribute__((ext_vector_type(8))) short bf16x8;
typedef __attribute__((ext_vector_type(4))) float f32x4;

__device__ __forceinline__ ushort f2bf(float f) {          // fp32 -> bf16 (RNE)
    unsigned u = __float_as_uint(f);
    return (ushort)((u + 0x7fffu + ((u >> 16) & 1u)) >> 16);
}
__device__ __forceinline__ float blo(unsigned u) { return __uint_as_float(u << 16); }
__device__ __forceinline__ float bhi(unsigned u) { return __uint_as_float(u & 0xffff0000u); }

// ---- K0: W -> bf16 W^T (for MFMA B-frags) + zero deg --------------------------
__global__ void k_wt(const float* __restrict__ W, ushort* __restrict__ Wt,
                     int* __restrict__ deg, int n) {
    int idx = blockIdx.x * 256 + threadIdx.x;
    if (idx < 16384) {
        int nn = idx >> 7, kk = idx & 127;
        Wt[idx] = f2bf(W[kk * 128 + nn]);      // Wt[nn][kk] = W[kk][nn]
    }
    if (idx < n) deg[idx] = 0;
}

// ---- K1: proj = A @ W via bf16 MFMA; fused scores ------------------------------
__global__ __launch_bounds__(256) void k_proj(const float* __restrict__ A,
                                              const ushort* __restrict__ Wt_g,
                                              const float* __restrict__ a_src,
                                              const float* __restrict__ a_tgt,
                                              ushort* __restrict__ Pb,
                                              float* __restrict__ ss,
                                              float* __restrict__ ts, int n) {
    __shared__ __align__(16) char smem[49152];  // [0,16K): A 64x128 bf16; [16K,48K): Wt 128x128 bf16
    const int tid = threadIdx.x;
    const int row0 = blockIdx.x * 64;

    // stage A rows (fp32 -> bf16), swizzled (byte ^= (row&7)<<4)
#pragma unroll
    for (int it = 0; it < 8; ++it) {
        int idx = it * 256 + tid;
        int r   = idx >> 5;
        int kc  = (idx & 31) << 2;
        int gr  = row0 + r;
        float4 v = make_float4(0.f, 0.f, 0.f, 0.f);
        if (gr < n) v = *(const float4*)&A[(size_t)gr * 128 + kc];
        ushort4 pk;
        pk.x = f2bf(v.x); pk.y = f2bf(v.y); pk.z = f2bf(v.z); pk.w = f2bf(v.w);
        *(ushort4*)(smem + ((r * 256 + kc * 2) ^ ((r & 7) << 4))) = pk;
    }
#pragma unroll
    for (int it = 0; it < 8; ++it) {
        int idx = it * 256 + tid;
        int nn  = idx >> 4;
        int k8  = (idx & 15) << 3;
        uint4 v = *(const uint4*)&Wt_g[nn * 128 + k8];
        *(uint4*)(smem + 16384 + ((nn * 256 + k8 * 2) ^ ((nn & 7) << 4))) = v;
    }
    __syncthreads();

    const int l  = tid & 63, w = tid >> 6;
    const int lr = l & 15,  lk = l >> 4;
    const int arow = w * 16 + lr;

    f32x4 acc[8] = {};
#pragma unroll
    for (int ks = 0; ks < 4; ++ks) {
        int kk = ks * 32 + lk * 8;
        bf16x8 af = *(const bf16x8*)(smem + ((arow * 256 + kk * 2) ^ ((arow & 7) << 4)));
#pragma unroll
        for (int nt = 0; nt < 8; ++nt) {
            int nn = nt * 16 + lr;
            bf16x8 bf = *(const bf16x8*)(smem + 16384 + ((nn * 256 + kk * 2) ^ ((nn & 7) << 4)));
            acc[nt] = __builtin_amdgcn_mfma_f32_16x16x32_bf16(af, bf, acc[nt], 0, 0, 0);
        }
    }

#pragma unroll
    for (int nt = 0; nt < 8; ++nt) {
#pragma unroll
        for (int r = 0; r < 4; ++r) {
            int gr = row0 + w * 16 + lk * 4 + r;
            if (gr < n) Pb[(size_t)gr * 128 + nt * 16 + lr] = f2bf(acc[nt][r]);
        }
    }

    float av[8], bw[8];
#pragma unroll
    for (int t = 0; t < 8; ++t) { av[t] = a_src[t * 16 + lr]; bw[t] = a_tgt[t * 16 + lr]; }
#pragma unroll
    for (int r = 0; r < 4; ++r) {
#pragma unroll
        for (int h = 0; h < 4; ++h) {
            float s1 = acc[2 * h][r] * av[2 * h] + acc[2 * h + 1][r] * av[2 * h + 1];
            float s2 = acc[2 * h][r] * bw[2 * h] + acc[2 * h + 1][r] * bw[2 * h + 1];
#pragma unroll
            for (int off = 1; off < 16; off <<= 1) {
                s1 += __shfl_xor(s1, off, 64);
                s2 += __shfl_xor(s2, off, 64);
            }
            if (lr == 0) {
                int gr = row0 + w * 16 + lk * 4 + r;
                if (gr < n) { ss[gr * 4 + h] = s1; ts[gr * 4 + h] = s2; }
            }
        }
    }
}

// ---------------- CSR build ----------------------------------------------------
__global__ void k_hist(const int* __restrict__ tgt, int* __restrict__ deg,
                       ushort* __restrict__ rank, int E) {
    int e = blockIdx.x * 256 + threadIdx.x;
    if (e < E) rank[e] = (ushort)atomicAdd(&deg[tgt[e]], 1);
}

// scan of PADDED degrees ((deg+3)&~3) -> CSR rows are multiples of 4
__global__ __launch_bounds__(256) void k_scan1(const int* __restrict__ deg,
                                               int* __restrict__ rowptr,
                                               int* __restrict__ sums, int n) {
    __shared__ int sd[256];
    int tid = threadIdx.x;
    int i = blockIdx.x * 256 + tid;
    int v = (i < n) ? ((deg[i] + 3) & ~3) : 0;
    sd[tid] = v; __syncthreads();
#pragma unroll
    for (int off = 1; off < 256; off <<= 1) {
        int t = (tid >= off) ? sd[tid - off] : 0;
        __syncthreads();
        sd[tid] += t;
        __syncthreads();
    }
    if (i < n) rowptr[i + 1] = sd[tid];
    if (tid == 255) sums[blockIdx.x] = sd[255];
}

__global__ __launch_bounds__(256) void k_scan23(int* __restrict__ rowptr,
                                                const int* __restrict__ sums,
                                                int nchunks, int n) {
    __shared__ int sd[256];
    int tid = threadIdx.x;
    int v = (tid < nchunks) ? sums[tid] : 0;
    sd[tid] = v; __syncthreads();
#pragma unroll
    for (int off = 1; off < 256; off <<= 1) {
        int t = (tid >= off) ? sd[tid - off] : 0;
        __syncthreads();
        sd[tid] += t;
        __syncthreads();
    }
    int b = blockIdx.x;
    int prefix = (b == 0) ? 0 : sd[b - 1];
    int i = b * 256 + tid;
    if (i < n) {
        rowptr[i + 1] += prefix;
        if (i == 0) rowptr[0] = 0;
    }
}

// ---- scatter (atomic-free) + pad-fill -----------------------------------------
__global__ void k_scatter(const int* __restrict__ src, const int* __restrict__ tgt,
                          const int* __restrict__ rowptr, const ushort* __restrict__ rank,
                          const int* __restrict__ deg, ushort* __restrict__ srcs,
                          int E, int n) {
    int e = blockIdx.x * 256 + threadIdx.x;
    if (e < E) {
        int t = tgt[e];
        srcs[rowptr[t] + rank[e]] = (ushort)src[e];
    } else {
        int i = e - E;
        if (i < n) {
            int j  = rowptr[i] + deg[i];
            int j1 = rowptr[i + 1];
            for (; j < j1; ++j) srcs[j] = 0xFFFFu;   // pad sentinel
        }
    }
}

// ---- aggregation: 1 wave/node, 8-deep gather MLP, vector-path loads -----------
// R8 lesson: scalar (SMEM) path for the per-edge loads serializes on the tiny
// constant cache -> keep srcs/ss/Pb on the VMEM path and widen ILP instead.
// Pads (0xFFFF) -> masked to row 0, score -1e30 -> exp 0 (NaN-free).
__global__ __launch_bounds__(256) void k_aggr(const int* __restrict__ rowptr,
                                              const ushort* __restrict__ srcs,
                                              const float* __restrict__ ss,
                                              const float* __restrict__ ts,
                                              const ushort* __restrict__ Pb,
                                              const float* __restrict__ bias,
                                              float* __restrict__ out, int n) {
    int node = __builtin_amdgcn_readfirstlane(blockIdx.x * 4 + (threadIdx.x >> 6));
    if (node >= n) return;
    const int lane = threadIdx.x & 63;
    const int c = lane * 2;
    const int h = lane >> 4;
    const float tsc = ts[node * 4 + h];
    const int b0 = rowptr[node], b1 = rowptr[node + 1];

    float ax0 = 0.f, ay0 = 0.f, ax1 = 0.f, ay1 = 0.f;
    float ax2 = 0.f, ay2 = 0.f, ax3 = 0.f, ay3 = 0.f;
    float den = 0.f;

    for (int i = b0; i < b1; i += 8) {
        uint2 ka = *(const uint2*)(srcs + i);
        uint2 kb;
        if (i + 4 < b1) kb = *(const uint2*)(srcs + i + 4);   // uniform branch
        else            kb = make_uint2(0xFFFFFFFFu, 0xFFFFFFFFu);
        int s0 = ka.x & 0xFFFF, s1 = ka.x >> 16, s2 = ka.y & 0xFFFF, s3 = ka.y >> 16;
        int s4 = kb.x & 0xFFFF, s5 = kb.x >> 16, s6 = kb.y & 0xFFFF, s7 = kb.y >> 16;
        bool v0 = s0 < n, v1 = s1 < n, v2 = s2 < n, v3 = s3 < n;
        bool v4 = s4 < n, v5 = s5 < n, v6 = s6 < n, v7 = s7 < n;
        int m0 = v0 ? s0 : 0, m1 = v1 ? s1 : 0, m2 = v2 ? s2 : 0, m3 = v3 ? s3 : 0;
        int m4 = v4 ? s4 : 0, m5 = v5 ? s5 : 0, m6 = v6 ? s6 : 0, m7 = v7 ? s7 : 0;
        // issue all 8 row-gathers + 8 score-gathers before any use (MLP)
        unsigned p0 = *(const unsigned*)(Pb + (size_t)m0 * 128 + c);
        unsigned p1 = *(const unsigned*)(Pb + (size_t)m1 * 128 + c);
        unsigned p2 = *(const unsigned*)(Pb + (size_t)m2 * 128 + c);
        unsigned p3 = *(const unsigned*)(Pb + (size_t)m3 * 128 + c);
        unsigned p4 = *(const unsigned*)(Pb + (size_t)m4 * 128 + c);
        unsigned p5 = *(const unsigned*)(Pb + (size_t)m5 * 128 + c);
        unsigned p6 = *(const unsigned*)(Pb + (size_t)m6 * 128 + c);
        unsigned p7 = *(const unsigned*)(Pb + (size_t)m7 * 128 + c);
        float sc0 = ss[m0 * 4 + h], sc1 = ss[m1 * 4 + h];
        float sc2 = ss[m2 * 4 + h], sc3 = ss[m3 * 4 + h];
        float sc4 = ss[m4 * 4 + h], sc5 = ss[m5 * 4 + h];
        float sc6 = ss[m6 * 4 + h], sc7 = ss[m7 * 4 + h];
        sc0 = v0 ? sc0 : -1e30f; sc1 = v1 ? sc1 : -1e30f;
        sc2 = v2 ? sc2 : -1e30f; sc3 = v3 ? sc3 : -1e30f;
        sc4 = v4 ? sc4 : -1e30f; sc5 = v5 ? sc5 : -1e30f;
        sc6 = v6 ? sc6 : -1e30f; sc7 = v7 ? sc7 : -1e30f;
        float w0 = sc0 + tsc; w0 = w0 > 0.f ? w0 : 0.2f * w0;  float e0 = __expf(w0);
        float w1 = sc1 + tsc; w1 = w1 > 0.f ? w1 : 0.2f * w1;  float e1 = __expf(w1);
        float w2 = sc2 + tsc; w2 = w2 > 0.f ? w2 : 0.2f * w2;  float e2 = __expf(w2);
        float w3 = sc3 + tsc; w3 = w3 > 0.f ? w3 : 0.2f * w3;  float e3 = __expf(w3);
        float w4 = sc4 + tsc; w4 = w4 > 0.f ? w4 : 0.2f * w4;  float e4 = __expf(w4);
        float w5 = sc5 + tsc; w5 = w5 > 0.f ? w5 : 0.2f * w5;  float e5 = __expf(w5);
        float w6 = sc6 + tsc; w6 = w6 > 0.f ? w6 : 0.2f * w6;  float e6 = __expf(w6);
        float w7 = sc7 + tsc; w7 = w7 > 0.f ? w7 : 0.2f * w7;  float e7 = __expf(w7);
        den += ((e0 + e1) + (e2 + e3)) + ((e4 + e5) + (e6 + e7));
        ax0 = fmaf(e0, blo(p0), ax0); ay0 = fmaf(e0, bhi(p0), ay0);
        ax1 = fmaf(e1, blo(p1), ax1); ay1 = fmaf(e1, bhi(p1), ay1);
        ax2 = fmaf(e2, blo(p2), ax2); ay2 = fmaf(e2, bhi(p2), ay2);
        ax3 = fmaf(e3, blo(p3), ax3); ay3 = fmaf(e3, bhi(p3), ay3);
        ax0 = fmaf(e4, blo(p4), ax0); ay0 = fmaf(e4, bhi(p4), ay0);
        ax1 = fmaf(e5, blo(p5), ax1); ay1 = fmaf(e5, bhi(p5), ay1);
        ax2 = fmaf(e6, blo(p6), ax2); ay2 = fmaf(e6, bhi(p6), ay2);
        ax3 = fmaf(e7, blo(p7), ax3); ay3 = fmaf(e7, bhi(p7), ay3);
    }
    float inv = 1.f / (den + 1e-16f);
    float2 bv = *(const float2*)&bias[c];
    float2 o;
    o.x = ((ax0 + ax1) + (ax2 + ax3)) * inv + bv.x;
    o.y = ((ay0 + ay1) + (ay2 + ay3)) * inv + bv.y;
    *(float2*)&out[(size_t)node * 128 + c] = o;
}

extern "C" void kernel_launch(void* const* d_in, const int* in_sizes, int n_in,
                              void* d_out, int out_size, void* d_ws, size_t ws_size,
                              hipStream_t stream) {
    const float* in_feat = (const float*)d_in[0];
    const int*   edge    = (const int*)d_in[1];
    const float* W_proj  = (const float*)d_in[3];
    const float* a_src   = (const float*)d_in[4];
    const float* a_tgt   = (const float*)d_in[5];
    const float* bias    = (const float*)d_in[6];
    float* out = (float*)d_out;

    const int n = in_sizes[0] / 128;   // 50000 (< 65536: ushort srcs/rank valid)
    const int E = in_sizes[1] / 2;     // 800000
    const int* src = edge;
    const int* tgt = edge + E;

    // workspace layout
    ushort* Pb   = (ushort*)d_ws;                      // n*128 bf16
    ushort* Wt_g = Pb + (size_t)n * 128;               // 128*128 bf16
    float*  ss   = (float*)(Wt_g + 128 * 128);         // n*4
    float*  ts   = ss + (size_t)n * 4;                 // n*4
    int* deg    = (int*)(ts + (size_t)n * 4);          // n
    int* rowptr = deg + n;                             // n+1
    int* sums   = rowptr + n + 1;                      // 256
    ushort* rank = (ushort*)(sums + 256);              // E
    ushort* srcs = rank + E;                           // E + 4n (padded CSR)

    const int nchunks = (n + 255) / 256;

    k_wt<<<(n + 255) / 256, 256, 0, stream>>>(W_proj, Wt_g, deg, n);
    k_hist<<<(E + 255) / 256, 256, 0, stream>>>(tgt, deg, rank, E);
    k_proj<<<(n + 63) / 64, 256, 0, stream>>>(in_feat, Wt_g, a_src, a_tgt,
                                              Pb, ss, ts, n);
    k_scan1<<<nchunks, 256, 0, stream>>>(deg, rowptr, sums, n);
    k_scan23<<<nchunks, 256, 0, stream>>>(rowptr, sums, nchunks, n);
    k_scatter<<<(E + n + 255) / 256, 256, 0, stream>>>(src, tgt, rowptr, rank,
                                                       deg, srcs, E, n);
    k_aggr<<<(n + 3) / 4, 256, 0, stream>>>(rowptr, srcs, ss, ts, Pb, bias, out, n);
}